// Round 5
// baseline (2422.897 us; speedup 1.0000x reference)
//
#include <hip/hip_runtime.h>
#include <hip/hip_bf16.h>

// VectorQuantizer B=32768, K=4096, D=512, fp32 in/out.
// Out concat (f32): quantized_st[B*512] | indices[B] | loss | perplexity | encodings[B*4096].
// Round 5: the np reference computes distances in FLOAT32; argmin must match its
// rounding. Emulate: numpy AVX512 pairwise row-sums for xsq/esq; OpenBLAS sgemm
// (seq-k fma, KC=384 split) for dot; d = fl(fl(xsq+esq) - fl(2*dot)); first-min.
// fp32 GEMM screen (top-3/thread, margin 2e-4) -> emulated rescore of candidates.

#define BB 32768
#define KK 4096
#define DD 512

#define IDX_OFF  (BB*DD)
#define LOSS_OFF (IDX_OFF + BB)
#define PERP_OFF (LOSS_OFF + 1)
#define ENC_OFF  (PERP_OFF + 1)

#define WS_XSQ  0
#define WS_ESQ  (WS_XSQ + BB)      // 32768
#define WS_IDX  (WS_ESQ + KK)      // 36864
#define WS_HIST (WS_IDX + BB)      // 69632
#define WS_LOSS (WS_HIST + KK)     // 73728 -> byte 294912 (8-aligned)

#define MARG 2.0e-4f
#define NCAND 24

__global__ __launch_bounds__(256) void init_kernel(int* __restrict__ hist,
                                                   double* __restrict__ loss_acc) {
    int i = blockIdx.x * 256 + threadIdx.x;
    if (i < KK) hist[i] = 0;
    if (i == 0) *loss_acc = 0.0;
}

// numpy-emulated row sum of squares: pairwise blocks of 128 with AVX512 SIMD
// inner (8 x 16-lane accumulators + _mm512_reduce_add_ps fold), blocks (B0+B1)+(B2+B3).
__global__ __launch_bounds__(256) void npsum_kernel(const float* __restrict__ X,
                                                    const float* __restrict__ E,
                                                    float* __restrict__ xsq,
                                                    float* __restrict__ esq) {
    __shared__ float sq[4][512];
    __shared__ float ub[4][64];
    __shared__ float bb[4][4];
    int w = threadIdx.x >> 6, lane = threadIdx.x & 63;
    int row = blockIdx.x * 4 + w;
    const float* src; float* dst;
    if (row < BB) { src = X + (size_t)row * DD;        dst = xsq + row; }
    else          { src = E + (size_t)(row - BB) * DD; dst = esq + (row - BB); }
    #pragma unroll
    for (int m = 0; m < 8; ++m) {
        float v = src[m * 64 + lane];
        sq[w][m * 64 + lane] = __fmul_rn(v, v);
    }
    __syncthreads();
    {   // lane = b*16+l : u[l] of 128-block b
        int b = lane >> 4, l = lane & 15;
        const float* s = &sq[w][b * 128];
        float t = __fadd_rn(
            __fadd_rn(__fadd_rn(s[l], s[16 + l]), __fadd_rn(s[32 + l], s[48 + l])),
            __fadd_rn(__fadd_rn(s[64 + l], s[80 + l]), __fadd_rn(s[96 + l], s[112 + l])));
        ub[w][lane] = t;
    }
    __syncthreads();
    if (lane < 4) {   // _mm512_reduce_add_ps fold of block `lane`
        const float* u = &ub[w][lane * 16];
        float T3[8], T6[4];
        #pragma unroll
        for (int i = 0; i < 8; ++i) T3[i] = __fadd_rn(u[i], u[i + 8]);
        #pragma unroll
        for (int i = 0; i < 4; ++i) T6[i] = __fadd_rn(T3[i], T3[i + 4]);
        bb[w][lane] = __fadd_rn(__fadd_rn(T6[0], T6[2]), __fadd_rn(T6[1], T6[3]));
    }
    __syncthreads();
    if (lane == 0)
        *dst = __fadd_rn(__fadd_rn(bb[w][0], bb[w][1]), __fadd_rn(bb[w][2], bb[w][3]));
}

#define BM 64
#define BN 256
#define BKC 32

__global__ __launch_bounds__(256, 2) void vq_main(
    const float* __restrict__ X, const float* __restrict__ E,
    const float* __restrict__ xsqw, const float* __restrict__ esqw,
    int* __restrict__ idxbuf, int* __restrict__ hist,
    double* __restrict__ loss_acc, float* __restrict__ out)
{
    __shared__ __align__(16) char smem[49408];
    float (*As)[BM + 4] = (float (*)[BM + 4])smem;            //  8704 B
    float (*Bs)[BN + 4] = (float (*)[BN + 4])(smem + 8704);   // 33280 B
    // post-GEMM aliasing:
    float (*rv0)[32] = (float (*)[32])smem;
    float (*rv1a)[32] = (float (*)[32])(smem + 8192);
    float (*rv2a)[32] = (float (*)[32])(smem + 16384);
    int   (*ri0)[32] = (int (*)[32])(smem + 24576);
    int   (*ri1a)[32] = (int (*)[32])(smem + 32768);
    int   (*ri2a)[32] = (int (*)[32])(smem + 40960);
    int*   sidx      = (int*)(smem + 49152);                  // 256 B

    const int tid = threadIdx.x;
    const int tx = tid & 31;
    const int ty = tid >> 5;
    const int row0 = blockIdx.x * BM;

    float v1[8], v2[8], v3[8];
    int   i1[8], i2[8], i3[8];
    #pragma unroll
    for (int i = 0; i < 8; ++i) {
        v1[i] = 3.0e38f; v2[i] = 3.0e38f; v3[i] = 3.0e38f;
        i1[i] = 0; i2[i] = 0; i3[i] = 0;
    }

    for (int nt = 0; nt < KK / BN; ++nt) {
        float acc[8][8];
        #pragma unroll
        for (int i = 0; i < 8; ++i)
            #pragma unroll
            for (int j = 0; j < 8; ++j) acc[i][j] = 0.f;

        for (int dk = 0; dk < DD; dk += BKC) {
            __syncthreads();
            {   // stage A
                int s = tid;
                #pragma unroll
                for (int it = 0; it < 2; ++it, s += 256) {
                    int r = s >> 3, d4 = (s & 7) * 4;
                    float4 v = *(const float4*)&X[(size_t)(row0 + r) * DD + dk + d4];
                    As[d4 + 0][r] = v.x; As[d4 + 1][r] = v.y;
                    As[d4 + 2][r] = v.z; As[d4 + 3][r] = v.w;
                }
            }
            {   // stage B
                int s = tid;
                #pragma unroll
                for (int it = 0; it < 8; ++it, s += 256) {
                    int c = s >> 3, d4 = (s & 7) * 4;
                    float4 v = *(const float4*)&E[(size_t)(nt * BN + c) * DD + dk + d4];
                    Bs[d4 + 0][c] = v.x; Bs[d4 + 1][c] = v.y;
                    Bs[d4 + 2][c] = v.z; Bs[d4 + 3][c] = v.w;
                }
            }
            __syncthreads();
            #pragma unroll 4
            for (int dd = 0; dd < BKC; ++dd) {
                float a[8], b[8];
                *(float4*)&a[0] = *(const float4*)&As[dd][ty * 8];
                *(float4*)&a[4] = *(const float4*)&As[dd][ty * 8 + 4];
                #pragma unroll
                for (int j = 0; j < 8; ++j) b[j] = Bs[dd][tx + 32 * j];
                #pragma unroll
                for (int i = 0; i < 8; ++i)
                    #pragma unroll
                    for (int j = 0; j < 8; ++j)
                        acc[i][j] = fmaf(a[i], b[j], acc[i][j]);
            }
        }
        #pragma unroll
        for (int j = 0; j < 8; ++j) {
            int gc = nt * BN + tx + 32 * j;
            float es = esqw[gc];
            #pragma unroll
            for (int i = 0; i < 8; ++i) {
                float s = fmaf(-2.0f, acc[i][j], es);
                if (s < v1[i]) { v3[i]=v2[i]; i3[i]=i2[i]; v2[i]=v1[i]; i2[i]=i1[i]; v1[i]=s; i1[i]=gc; }
                else if (s < v2[i]) { v3[i]=v2[i]; i3[i]=i2[i]; v2[i]=s; i2[i]=gc; }
                else if (s < v3[i]) { v3[i]=s; i3[i]=gc; }
            }
        }
    }
    __syncthreads();
    #pragma unroll
    for (int i = 0; i < 8; ++i) {
        rv0[ty*8+i][tx] = v1[i];  ri0[ty*8+i][tx] = i1[i];
        rv1a[ty*8+i][tx] = v2[i]; ri1a[ty*8+i][tx] = i2[i];
        rv2a[ty*8+i][tx] = v3[i]; ri2a[ty*8+i][tx] = i3[i];
    }
    __syncthreads();
    if (tid < BM) {
        const int row = tid;
        float m = rv0[row][0];
        #pragma unroll
        for (int t = 1; t < 32; ++t) m = fminf(m, rv0[row][t]);
        float lim = m + MARG;
        int cand[NCAND]; int nc = 0;
        for (int t = 0; t < 32; ++t) {
            if (rv0[row][t]  <= lim && nc < NCAND) cand[nc++] = ri0[row][t];
            if (rv1a[row][t] <= lim && nc < NCAND) cand[nc++] = ri1a[row][t];
            if (rv2a[row][t] <= lim && nc < NCAND) cand[nc++] = ri2a[row][t];
        }
        // numpy-fp32 emulated rescore:
        // d = fl(fl(xsq+esq) - fl(2*dot)), dot = fl(P[0,384) + P[384,512)),
        // each P a sequential-k fmaf chain (OpenBLAS microkernel order).
        const float* xr = X + (size_t)(row0 + row) * DD;
        float xs = xsqw[row0 + row];
        float bd = 3.0e38f; int bk = 0x7fffffff;
        for (int c = 0; c < nc; ++c) {
            int k = cand[c] & (KK - 1);
            const float* er = E + (size_t)k * DD;
            float p1 = 0.f, p2 = 0.f;
            for (int d = 0; d < 384; ++d)   p1 = fmaf(xr[d], er[d], p1);
            for (int d = 384; d < 512; ++d) p2 = fmaf(xr[d], er[d], p2);
            float dot = __fadd_rn(p1, p2);
            float t1  = __fadd_rn(xs, esqw[k]);
            float dnp = __fsub_rn(t1, __fmul_rn(2.0f, dot));
            if (dnp < bd || (dnp == bd && k < bk)) { bd = dnp; bk = k; }
        }
        // exact fp64 loss contribution for chosen code
        const float* er = E + (size_t)bk * DD;
        double ls = 0.0;
        for (int d = 0; d < DD; ++d) {
            double df = (double)xr[d] - (double)er[d];
            ls = fma(df, df, ls);
        }
        atomicAdd(loss_acc, ls);
        sidx[row] = bk;
        idxbuf[row0 + row] = bk;
        out[IDX_OFF + row0 + row] = (float)bk;
        atomicAdd(&hist[bk], 1);
    }
    __syncthreads();
    // quantized_st = codebook gather (ref differs by ~1e-7, threshold loose)
    for (int e = tid; e < BM * DD / 4; e += 256) {
        int r = e >> 7, d = (e & 127) * 4;
        int ci = sidx[r];
        float4 q4 = *(const float4*)&E[(size_t)ci * DD + d];
        *(float4*)&out[(size_t)(row0 + r) * DD + d] = q4;
    }
}

__global__ __launch_bounds__(256) void enc_kernel(const int* __restrict__ idxbuf,
                                                  float* __restrict__ out) {
    int row = blockIdx.x;
    int idx = idxbuf[row];
    float2* erow = (float2*)(out + ENC_OFF) + (size_t)row * (KK / 2);
    int half = idx >> 1;
    float2 one;
    if (idx & 1) { one.x = 0.f; one.y = 1.f; } else { one.x = 1.f; one.y = 0.f; }
    float2 z; z.x = 0.f; z.y = 0.f;
    for (int c = threadIdx.x; c < KK / 2; c += 256)
        erow[c] = (c == half) ? one : z;
}

__global__ __launch_bounds__(256) void fin_kernel(const int* __restrict__ hist,
                                                  const double* __restrict__ loss_acc,
                                                  float* __restrict__ out) {
    __shared__ double red[256];
    int tid = threadIdx.x;
    double s = 0.0;
    for (int k = tid; k < KK; k += 256) {
        double p = (double)hist[k] * (1.0 / 32768.0);
        s += p * log(p + 1e-10);
    }
    red[tid] = s;
    __syncthreads();
    for (int t = 128; t > 0; t >>= 1) {
        if (tid < t) red[tid] += red[tid + t];
        __syncthreads();
    }
    if (tid == 0) {
        double perp = exp(-red[0]);
        double L = loss_acc[0] * (1.0 / ((double)BB * (double)DD));
        out[LOSS_OFF] = (float)(1.25 * L);
        out[PERP_OFF] = (float)perp;
    }
}

extern "C" void kernel_launch(void* const* d_in, const int* in_sizes, int n_in,
                              void* d_out, int out_size, void* d_ws, size_t ws_size,
                              hipStream_t stream) {
    const float* X; const float* E;
    if (in_sizes[0] == BB * DD) { X = (const float*)d_in[0]; E = (const float*)d_in[1]; }
    else                        { X = (const float*)d_in[1]; E = (const float*)d_in[0]; }
    float* out = (float*)d_out;

    float* xsq = (float*)d_ws + WS_XSQ;
    float* esq = (float*)d_ws + WS_ESQ;
    int* idxbuf = (int*)d_ws + WS_IDX;
    int* hist   = (int*)d_ws + WS_HIST;
    double* loss_acc = (double*)((char*)d_ws + (size_t)WS_LOSS * 4);

    hipLaunchKernelGGL(init_kernel, dim3(16), dim3(256), 0, stream, hist, loss_acc);
    hipLaunchKernelGGL(npsum_kernel, dim3((BB + KK) / 4), dim3(256), 0, stream,
                       X, E, xsq, esq);
    hipLaunchKernelGGL(vq_main, dim3(BB / BM), dim3(256), 0, stream,
                       X, E, xsq, esq, idxbuf, hist, loss_acc, out);
    hipLaunchKernelGGL(enc_kernel, dim3(BB), dim3(256), 0, stream, idxbuf, out);
    hipLaunchKernelGGL(fin_kernel, dim3(1), dim3(256), 0, stream, hist, loss_acc, out);
}

// Round 6
// 604.728 us; speedup vs baseline: 4.0066x; 4.0066x over previous
//
#include <hip/hip_runtime.h>
#include <hip/hip_bf16.h>

// VectorQuantizer B=32768, K=4096, D=512, fp32 in/out.
// Out concat (f32): quantized_st[B*512] | indices[B] | loss | perplexity | encodings[B*4096].
// R6: bf16 MFMA screening GEMM (error ~1e-5 << margin 2.5e-4) + byte-identical
// numpy-fp32 rescore from R5 (which passed with exact indices). A-frags live in
// registers for the whole K-sweep; B double-buffered in padded LDS (conflict-free
// b128); loss reduced per-block before one fp64 atomic.

typedef __attribute__((ext_vector_type(8))) short bf16x8;
typedef __attribute__((ext_vector_type(4))) float f32x4;

#define BB 32768
#define KK 4096
#define DD 512

#define IDX_OFF  (BB*DD)
#define LOSS_OFF (IDX_OFF + BB)
#define PERP_OFF (LOSS_OFF + 1)
#define ENC_OFF  (PERP_OFF + 1)

// ws byte offsets
#define WSB_XSQ  0
#define WSB_ESQ  131072
#define WSB_IDX  147456
#define WSB_HIST 278528
#define WSB_LOSS 294912
#define WSB_EBF  294928        // 4 MB of bf16 codebook

#define MARG 2.5e-4f
#define NCAND 24

static __device__ __forceinline__ unsigned short f2bf(float f) {
    __hip_bfloat16 h = __float2bfloat16(f);
    return *reinterpret_cast<unsigned short*>(&h);
}

__global__ __launch_bounds__(256) void init_kernel(int* __restrict__ hist,
                                                   double* __restrict__ loss_acc) {
    int i = blockIdx.x * 256 + threadIdx.x;
    if (i < KK) hist[i] = 0;
    if (i == 0) *loss_acc = 0.0;
}

// numpy-emulated row sum-of-squares (pairwise-128 + AVX512 lane fold) — unchanged from R5
__global__ __launch_bounds__(256) void npsum_kernel(const float* __restrict__ X,
                                                    const float* __restrict__ E,
                                                    float* __restrict__ xsq,
                                                    float* __restrict__ esq) {
    __shared__ float sq[4][512];
    __shared__ float ub[4][64];
    __shared__ float bb[4][4];
    int w = threadIdx.x >> 6, lane = threadIdx.x & 63;
    int row = blockIdx.x * 4 + w;
    const float* src; float* dst;
    if (row < BB) { src = X + (size_t)row * DD;        dst = xsq + row; }
    else          { src = E + (size_t)(row - BB) * DD; dst = esq + (row - BB); }
    #pragma unroll
    for (int m = 0; m < 8; ++m) {
        float v = src[m * 64 + lane];
        sq[w][m * 64 + lane] = __fmul_rn(v, v);
    }
    __syncthreads();
    {
        int b = lane >> 4, l = lane & 15;
        const float* s = &sq[w][b * 128];
        float t = __fadd_rn(
            __fadd_rn(__fadd_rn(s[l], s[16 + l]), __fadd_rn(s[32 + l], s[48 + l])),
            __fadd_rn(__fadd_rn(s[64 + l], s[80 + l]), __fadd_rn(s[96 + l], s[112 + l])));
        ub[w][lane] = t;
    }
    __syncthreads();
    if (lane < 4) {
        const float* u = &ub[w][lane * 16];
        float T3[8], T6[4];
        #pragma unroll
        for (int i = 0; i < 8; ++i) T3[i] = __fadd_rn(u[i], u[i + 8]);
        #pragma unroll
        for (int i = 0; i < 4; ++i) T6[i] = __fadd_rn(T3[i], T3[i + 4]);
        bb[w][lane] = __fadd_rn(__fadd_rn(T6[0], T6[2]), __fadd_rn(T6[1], T6[3]));
    }
    __syncthreads();
    if (lane == 0)
        *dst = __fadd_rn(__fadd_rn(bb[w][0], bb[w][1]), __fadd_rn(bb[w][2], bb[w][3]));
}

// codebook fp32 -> bf16 (screening operand)
__global__ __launch_bounds__(256) void ecvt_kernel(const float* __restrict__ E,
                                                   unsigned short* __restrict__ Ebf) {
    int t = blockIdx.x * 256 + threadIdx.x;
    const float4* s = (const float4*)(E + (size_t)t * 8);
    float4 a = s[0], b = s[1];
    union { bf16x8 v; unsigned short u[8]; } pk;
    pk.u[0] = f2bf(a.x); pk.u[1] = f2bf(a.y); pk.u[2] = f2bf(a.z); pk.u[3] = f2bf(a.w);
    pk.u[4] = f2bf(b.x); pk.u[5] = f2bf(b.y); pk.u[6] = f2bf(b.z); pk.u[7] = f2bf(b.w);
    *(bf16x8*)(Ebf + (size_t)t * 8) = pk.v;
}

// main: bf16 MFMA screen (top-2/lane/row) -> numpy-fp32 rescore -> epilogues
__global__ __launch_bounds__(256, 2) void vq_main(
    const float* __restrict__ X, const float* __restrict__ E,
    const unsigned short* __restrict__ Ebf,
    const float* __restrict__ xsqw, const float* __restrict__ esqw,
    int* __restrict__ idxbuf, int* __restrict__ hist,
    double* __restrict__ loss_acc, float* __restrict__ out)
{
    __shared__ __align__(16) char pool[40960];

    const int tid = threadIdx.x;
    const int lane = tid & 63;
    const int w = tid >> 6;       // wave 0..3 -> rows w*16..w*16+15
    const int g = lane >> 4;      // k-group
    const int c = lane & 15;      // col-in-frag / row-in-A
    const int row0 = blockIdx.x * 64;

    // ---- phase A: A-frags to registers via two half-K LDS stages ----
    bf16x8 afrag[16];
    {
        unsigned short* Ash = (unsigned short*)pool;   // [64][264] halfwords (33,792 B)
        #pragma unroll
        for (int half = 0; half < 2; ++half) {
            int koff = half * 256;
            #pragma unroll
            for (int it = 0; it < 8; ++it) {
                int idx = it * 2048 + tid * 8;
                int r = idx >> 8, k = idx & 255;
                const float4* src = (const float4*)&X[(size_t)(row0 + r) * DD + koff + k];
                float4 va = src[0], vb = src[1];
                union { bf16x8 v; unsigned short u[8]; } pk;
                pk.u[0] = f2bf(va.x); pk.u[1] = f2bf(va.y);
                pk.u[2] = f2bf(va.z); pk.u[3] = f2bf(va.w);
                pk.u[4] = f2bf(vb.x); pk.u[5] = f2bf(vb.y);
                pk.u[6] = f2bf(vb.z); pk.u[7] = f2bf(vb.w);
                *(bf16x8*)&Ash[r * 264 + k] = pk.v;
            }
            __syncthreads();
            int arow = w * 16 + c;
            #pragma unroll
            for (int ks = 0; ks < 8; ++ks)
                afrag[half * 8 + ks] = *(const bf16x8*)&Ash[arow * 264 + ks * 32 + g * 8];
            __syncthreads();
        }
    }

    // ---- phase B: nt loop over 16 col-tiles of 256, double-buffered BK=32 ----
    unsigned short* Bbuf0 = (unsigned short*)pool;            // [256][40] halfwords, 20,480 B
    unsigned short* Bbuf1 = (unsigned short*)(pool + 20480);

    f32x4 acc[16];
    #pragma unroll
    for (int i = 0; i < 16; ++i) acc[i] = (f32x4){0.f, 0.f, 0.f, 0.f};
    float v1[4], v2[4]; int i1[4], i2[4];
    #pragma unroll
    for (int r = 0; r < 4; ++r) { v1[r] = 3.0e38f; v2[r] = 3.0e38f; i1[r] = 0; i2[r] = 0; }

    bf16x8 rg0, rg1, rg2, rg3;
    #define GLOAD(nt_, ks_) { \
        const bf16x8* src_ = (const bf16x8*)Ebf + ((size_t)((nt_) * 256 + tid) * 64 + (ks_) * 4); \
        rg0 = src_[0]; rg1 = src_[1]; rg2 = src_[2]; rg3 = src_[3]; }
    #define LWRITE(buf_) { \
        unsigned short* d_ = (buf_) + tid * 40; \
        *(bf16x8*)&d_[0] = rg0; *(bf16x8*)&d_[8] = rg1; \
        *(bf16x8*)&d_[16] = rg2; *(bf16x8*)&d_[24] = rg3; }

    GLOAD(0, 0); LWRITE(Bbuf0);
    __syncthreads();
    int cur = 0;
    for (int nt = 0; nt < 16; ++nt) {
        #pragma unroll
        for (int ks = 0; ks < 16; ++ks) {
            int t = nt * 16 + ks;
            if (t < 255) { int t2 = t + 1; GLOAD(t2 >> 4, t2 & 15); }
            const unsigned short* B = cur ? Bbuf1 : Bbuf0;
            #pragma unroll
            for (int fj = 0; fj < 16; ++fj) {
                bf16x8 b = *(const bf16x8*)&B[(fj * 16 + c) * 40 + g * 8];
                acc[fj] = __builtin_amdgcn_mfma_f32_16x16x32_bf16(afrag[ks], b, acc[fj], 0, 0, 0);
            }
            __syncthreads();                       // all reads of buf[cur] done
            if (t < 255) LWRITE(cur ? Bbuf0 : Bbuf1);
            __syncthreads();                       // writes visible
            cur ^= 1;
        }
        // epilogue: screening scores s = esq - 2*dot, per-lane per-row top-2
        #pragma unroll
        for (int fj = 0; fj < 16; ++fj) {
            int gc = nt * 256 + fj * 16 + c;
            float es = esqw[gc];
            #pragma unroll
            for (int r = 0; r < 4; ++r) {
                float s = fmaf(-2.0f, acc[fj][r], es);
                if (s < v1[r]) { v2[r] = v1[r]; i2[r] = i1[r]; v1[r] = s; i1[r] = gc; }
                else if (s < v2[r]) { v2[r] = s; i2[r] = gc; }
            }
            acc[fj] = (f32x4){0.f, 0.f, 0.f, 0.f};
        }
    }

    // ---- merge + rescore ----
    __syncthreads();
    float*  mv1 = (float*)pool;                  // [64][16]
    float*  mv2 = (float*)(pool + 4096);
    int*    mi1 = (int*)(pool + 8192);
    int*    mi2 = (int*)(pool + 12288);
    int*    sidx = (int*)(pool + 16384);         // 64
    double* lsr  = (double*)(pool + 16640);      // 64
    #pragma unroll
    for (int r = 0; r < 4; ++r) {
        int mrow = w * 16 + g * 4 + r;
        mv1[mrow * 16 + c] = v1[r];  mi1[mrow * 16 + c] = i1[r];
        mv2[mrow * 16 + c] = v2[r];  mi2[mrow * 16 + c] = i2[r];
    }
    __syncthreads();
    if (tid < 64) {
        const int row = tid;
        float m = mv1[row * 16];
        #pragma unroll
        for (int t = 1; t < 16; ++t) m = fminf(m, mv1[row * 16 + t]);
        float lim = m + MARG;
        int cand[NCAND]; int nc = 0;
        for (int t = 0; t < 16; ++t) {
            if (mv1[row * 16 + t] <= lim && nc < NCAND) cand[nc++] = mi1[row * 16 + t];
            if (mv2[row * 16 + t] <= lim && nc < NCAND) cand[nc++] = mi2[row * 16 + t];
        }
        // numpy-fp32 emulated rescore (verbatim from R5, which passed exactly)
        const float* xr = X + (size_t)(row0 + row) * DD;
        float xs = xsqw[row0 + row];
        float bd = 3.0e38f; int bk = 0x7fffffff;
        for (int cidx = 0; cidx < nc; ++cidx) {
            int k = cand[cidx] & (KK - 1);
            const float* er = E + (size_t)k * DD;
            float p1 = 0.f, p2 = 0.f;
            for (int d = 0; d < 384; ++d)   p1 = fmaf(xr[d], er[d], p1);
            for (int d = 384; d < 512; ++d) p2 = fmaf(xr[d], er[d], p2);
            float dot = __fadd_rn(p1, p2);
            float t1  = __fadd_rn(xs, esqw[k]);
            float dnp = __fsub_rn(t1, __fmul_rn(2.0f, dot));
            if (dnp < bd || (dnp == bd && k < bk)) { bd = dnp; bk = k; }
        }
        const float* er = E + (size_t)bk * DD;
        double ls = 0.0;
        for (int d = 0; d < DD; ++d) {
            double df = (double)xr[d] - (double)er[d];
            ls = fma(df, df, ls);
        }
        lsr[row] = ls;
        sidx[row] = bk;
        idxbuf[row0 + row] = bk;
        out[IDX_OFF + row0 + row] = (float)bk;
        atomicAdd(&hist[bk], 1);
    }
    __syncthreads();
    // quantized_st = codebook gather, fp32
    for (int e = tid; e < 64 * DD / 4; e += 256) {
        int r = e >> 7, d = (e & 127) * 4;
        int ci = sidx[r];
        float4 q4 = *(const float4*)&E[(size_t)ci * DD + d];
        *(float4*)&out[(size_t)(row0 + r) * DD + d] = q4;
    }
    if (tid == 0) {
        double s = 0.0;
        for (int i = 0; i < 64; ++i) s += lsr[i];
        atomicAdd(loss_acc, s);
    }
    #undef GLOAD
    #undef LWRITE
}

__global__ __launch_bounds__(256) void enc_kernel(const int* __restrict__ idxbuf,
                                                  float* __restrict__ out) {
    int row = blockIdx.x;
    int idx = idxbuf[row];
    float2* erow = (float2*)(out + ENC_OFF) + (size_t)row * (KK / 2);
    int half = idx >> 1;
    float2 one;
    if (idx & 1) { one.x = 0.f; one.y = 1.f; } else { one.x = 1.f; one.y = 0.f; }
    float2 z; z.x = 0.f; z.y = 0.f;
    for (int c = threadIdx.x; c < KK / 2; c += 256)
        erow[c] = (c == half) ? one : z;
}

__global__ __launch_bounds__(256) void fin_kernel(const int* __restrict__ hist,
                                                  const double* __restrict__ loss_acc,
                                                  float* __restrict__ out) {
    __shared__ double red[256];
    int tid = threadIdx.x;
    double s = 0.0;
    for (int k = tid; k < KK; k += 256) {
        double p = (double)hist[k] * (1.0 / 32768.0);
        s += p * log(p + 1e-10);
    }
    red[tid] = s;
    __syncthreads();
    for (int t = 128; t > 0; t >>= 1) {
        if (tid < t) red[tid] += red[tid + t];
        __syncthreads();
    }
    if (tid == 0) {
        double perp = exp(-red[0]);
        double L = loss_acc[0] * (1.0 / ((double)BB * (double)DD));
        out[LOSS_OFF] = (float)(1.25 * L);
        out[PERP_OFF] = (float)perp;
    }
}

extern "C" void kernel_launch(void* const* d_in, const int* in_sizes, int n_in,
                              void* d_out, int out_size, void* d_ws, size_t ws_size,
                              hipStream_t stream) {
    const float* X; const float* E;
    if (in_sizes[0] == BB * DD) { X = (const float*)d_in[0]; E = (const float*)d_in[1]; }
    else                        { X = (const float*)d_in[1]; E = (const float*)d_in[0]; }
    float* out = (float*)d_out;

    float* xsq = (float*)((char*)d_ws + WSB_XSQ);
    float* esq = (float*)((char*)d_ws + WSB_ESQ);
    int* idxbuf = (int*)((char*)d_ws + WSB_IDX);
    int* hist   = (int*)((char*)d_ws + WSB_HIST);
    double* loss_acc = (double*)((char*)d_ws + WSB_LOSS);
    unsigned short* Ebf = (unsigned short*)((char*)d_ws + WSB_EBF);

    hipLaunchKernelGGL(init_kernel, dim3(16), dim3(256), 0, stream, hist, loss_acc);
    hipLaunchKernelGGL(npsum_kernel, dim3((BB + KK) / 4), dim3(256), 0, stream,
                       X, E, xsq, esq);
    hipLaunchKernelGGL(ecvt_kernel, dim3(KK * DD / (256 * 8)), dim3(256), 0, stream, E, Ebf);
    hipLaunchKernelGGL(vq_main, dim3(BB / 64), dim3(256), 0, stream,
                       X, E, Ebf, xsq, esq, idxbuf, hist, loss_acc, out);
    hipLaunchKernelGGL(enc_kernel, dim3(BB), dim3(256), 0, stream, idxbuf, out);
    hipLaunchKernelGGL(fin_kernel, dim3(1), dim3(256), 0, stream, hist, loss_acc, out);
}

// Round 7
// 579.093 us; speedup vs baseline: 4.1839x; 1.0443x over previous
//
#include <hip/hip_runtime.h>
#include <hip/hip_bf16.h>

// VectorQuantizer B=32768, K=4096, D=512, fp32 in/out.
// Out concat (f32): quantized_st[B*512] | indices[B] | loss | perplexity | encodings[B*4096].
// R7: barrier-free MFMA screen. Ebf pre-packed in fragment order so each B-frag
// is one coalesced global_load_dwordx4 from L2 (no LDS staging in the K-loop).
// 32 rows/wave (A frags full-K in 128 VGPRs), 2 waves/block splitting columns.
// Packed (score|col) top-2 per lane-slot; numpy-fp32 rescore verbatim from R5/R6.

typedef __attribute__((ext_vector_type(8))) short bf16x8;
typedef __attribute__((ext_vector_type(4))) float f32x4;

#define BB 32768
#define KK 4096
#define DD 512

#define IDX_OFF  (BB*DD)
#define LOSS_OFF (IDX_OFF + BB)
#define PERP_OFF (LOSS_OFF + 1)
#define ENC_OFF  (PERP_OFF + 1)

// ws byte offsets (same as R6)
#define WSB_XSQ  0
#define WSB_ESQ  131072
#define WSB_IDX  147456
#define WSB_HIST 278528
#define WSB_LOSS 294912
#define WSB_EBF  294928        // 4 MB bf16 codebook, fragment-packed

#define MARG 2.5e-4f
#define NCAND 24

static __device__ __forceinline__ unsigned short f2bf(float f) {
    __hip_bfloat16 h = __float2bfloat16(f);
    return *reinterpret_cast<unsigned short*>(&h);
}

// monotone-packed score: high 20 bits = order-preserving float bits, low 12 = col
static __device__ __forceinline__ unsigned int packscore(float s, int col) {
    unsigned int u = __float_as_uint(s);
    u ^= (u & 0x80000000u) ? 0xFFFFFFFFu : 0x80000000u;
    return (u & 0xFFFFF000u) | (unsigned int)col;
}
static __device__ __forceinline__ float unpackscore(unsigned int p) {
    unsigned int u = p & 0xFFFFF000u;
    u = (u & 0x80000000u) ? (u ^ 0x80000000u) : ~u;
    return __uint_as_float(u);
}

__global__ __launch_bounds__(256) void init_kernel(int* __restrict__ hist,
                                                   double* __restrict__ loss_acc) {
    int i = blockIdx.x * 256 + threadIdx.x;
    if (i < KK) hist[i] = 0;
    if (i == 0) *loss_acc = 0.0;
}

// numpy-emulated row sum-of-squares (pairwise-128 + AVX512 lane fold) — validated R5/R6
__global__ __launch_bounds__(256) void npsum_kernel(const float* __restrict__ X,
                                                    const float* __restrict__ E,
                                                    float* __restrict__ xsq,
                                                    float* __restrict__ esq) {
    __shared__ float sq[4][512];
    __shared__ float ub[4][64];
    __shared__ float bb[4][4];
    int w = threadIdx.x >> 6, lane = threadIdx.x & 63;
    int row = blockIdx.x * 4 + w;
    const float* src; float* dst;
    if (row < BB) { src = X + (size_t)row * DD;        dst = xsq + row; }
    else          { src = E + (size_t)(row - BB) * DD; dst = esq + (row - BB); }
    #pragma unroll
    for (int m = 0; m < 8; ++m) {
        float v = src[m * 64 + lane];
        sq[w][m * 64 + lane] = __fmul_rn(v, v);
    }
    __syncthreads();
    {
        int b = lane >> 4, l = lane & 15;
        const float* s = &sq[w][b * 128];
        float t = __fadd_rn(
            __fadd_rn(__fadd_rn(s[l], s[16 + l]), __fadd_rn(s[32 + l], s[48 + l])),
            __fadd_rn(__fadd_rn(s[64 + l], s[80 + l]), __fadd_rn(s[96 + l], s[112 + l])));
        ub[w][lane] = t;
    }
    __syncthreads();
    if (lane < 4) {
        const float* u = &ub[w][lane * 16];
        float T3[8], T6[4];
        #pragma unroll
        for (int i = 0; i < 8; ++i) T3[i] = __fadd_rn(u[i], u[i + 8]);
        #pragma unroll
        for (int i = 0; i < 4; ++i) T6[i] = __fadd_rn(T3[i], T3[i + 4]);
        bb[w][lane] = __fadd_rn(__fadd_rn(T6[0], T6[2]), __fadd_rn(T6[1], T6[3]));
    }
    __syncthreads();
    if (lane == 0)
        *dst = __fadd_rn(__fadd_rn(bb[w][0], bb[w][1]), __fadd_rn(bb[w][2], bb[w][3]));
}

// codebook fp32 -> bf16, FRAGMENT-PACKED: element (cf,ks,lane=c+16g,j) at
// halfword ((cf*16+ks)*64+lane)*8+j holds E[cf*16+c][ks*32+g*8+j].
__global__ __launch_bounds__(256) void ecvt_kernel(const float* __restrict__ E,
                                                   unsigned short* __restrict__ Ebf) {
    int t = blockIdx.x * 256 + threadIdx.x;     // 262144 threads
    int lane = t & 63, rest = t >> 6;
    int ks = rest & 15, cf = rest >> 4;
    int c = lane & 15, g = lane >> 4;
    const float* src = E + (size_t)(cf * 16 + c) * DD + ks * 32 + g * 8;
    float4 a = ((const float4*)src)[0], b = ((const float4*)src)[1];
    union { bf16x8 v; unsigned short u[8]; } pk;
    pk.u[0] = f2bf(a.x); pk.u[1] = f2bf(a.y); pk.u[2] = f2bf(a.z); pk.u[3] = f2bf(a.w);
    pk.u[4] = f2bf(b.x); pk.u[5] = f2bf(b.y); pk.u[6] = f2bf(b.z); pk.u[7] = f2bf(b.w);
    *(bf16x8*)(Ebf + (size_t)t * 8) = pk.v;
}

// main: barrier-free bf16 MFMA screen -> numpy-fp32 rescore -> epilogues.
// block = 128 threads (2 waves), 32 rows; wave w covers cols w*2048..+2047.
__global__ __launch_bounds__(128, 2) void vq_mfma(
    const float* __restrict__ X, const float* __restrict__ E,
    const unsigned short* __restrict__ Ebf,
    const float* __restrict__ xsqw, const float* __restrict__ esqw,
    int* __restrict__ idxbuf, int* __restrict__ hist,
    double* __restrict__ loss_acc, float* __restrict__ out)
{
    __shared__ unsigned int P1[2][32][16];
    __shared__ unsigned int P2[2][32][16];
    __shared__ int    sidx[32];
    __shared__ double lsr[32];

    const int tid  = threadIdx.x;
    const int w    = tid >> 6;
    const int lane = tid & 63;
    const int c    = lane & 15;
    const int g    = lane >> 4;
    const int row0 = blockIdx.x * 32;

    // ---- A fragments, full K, in registers: rows rf*16 + c ----
    bf16x8 afrag[2][16];
    #pragma unroll
    for (int rf = 0; rf < 2; ++rf) {
        const float* xrow = X + (size_t)(row0 + rf * 16 + c) * DD;
        #pragma unroll
        for (int ks = 0; ks < 16; ++ks) {
            const float4* s = (const float4*)(xrow + ks * 32 + g * 8);
            float4 a = s[0], b = s[1];
            union { bf16x8 v; unsigned short u[8]; } pk;
            pk.u[0] = f2bf(a.x); pk.u[1] = f2bf(a.y);
            pk.u[2] = f2bf(a.z); pk.u[3] = f2bf(a.w);
            pk.u[4] = f2bf(b.x); pk.u[5] = f2bf(b.y);
            pk.u[6] = f2bf(b.z); pk.u[7] = f2bf(b.w);
            afrag[rf][ks] = pk.v;
        }
    }

    unsigned int p1[2][4], p2[2][4];
    #pragma unroll
    for (int rf = 0; rf < 2; ++rf)
        #pragma unroll
        for (int r = 0; r < 4; ++r) { p1[rf][r] = 0xFFFFFFFFu; p2[rf][r] = 0xFFFFFFFFu; }

    // ---- K-loop: 128 col-frags per wave, no barriers, B straight from L2 ----
    const int cf0 = w * 128;
    for (int cfl = 0; cfl < 128; ++cfl) {
        const int cf = cf0 + cfl;
        const bf16x8* bsrc = (const bf16x8*)Ebf + ((size_t)cf * 16) * 64 + lane;
        f32x4 acc0 = (f32x4){0.f, 0.f, 0.f, 0.f};
        f32x4 acc1 = (f32x4){0.f, 0.f, 0.f, 0.f};
        #pragma unroll
        for (int kh = 0; kh < 2; ++kh) {
            bf16x8 b[8];
            #pragma unroll
            for (int ks = 0; ks < 8; ++ks) b[ks] = bsrc[(kh * 8 + ks) * 64];
            #pragma unroll
            for (int ks = 0; ks < 8; ++ks) {
                acc0 = __builtin_amdgcn_mfma_f32_16x16x32_bf16(afrag[0][kh * 8 + ks], b[ks], acc0, 0, 0, 0);
                acc1 = __builtin_amdgcn_mfma_f32_16x16x32_bf16(afrag[1][kh * 8 + ks], b[ks], acc1, 0, 0, 0);
            }
        }
        const int col = cf * 16 + c;
        const float esqc = esqw[col];
        #pragma unroll
        for (int r = 0; r < 4; ++r) {
            float s0 = fmaf(-2.0f, acc0[r], esqc);
            unsigned int q0 = packscore(s0, col);
            if (q0 < p1[0][r]) { p2[0][r] = p1[0][r]; p1[0][r] = q0; }
            else if (q0 < p2[0][r]) p2[0][r] = q0;
            float s1 = fmaf(-2.0f, acc1[r], esqc);
            unsigned int q1 = packscore(s1, col);
            if (q1 < p1[1][r]) { p2[1][r] = p1[1][r]; p1[1][r] = q1; }
            else if (q1 < p2[1][r]) p2[1][r] = q1;
        }
    }

    // ---- merge via LDS ----
    #pragma unroll
    for (int rf = 0; rf < 2; ++rf)
        #pragma unroll
        for (int r = 0; r < 4; ++r) {
            int row = rf * 16 + g * 4 + r;
            P1[w][row][c] = p1[rf][r];
            P2[w][row][c] = p2[rf][r];
        }
    __syncthreads();

    if (tid < 32) {
        const int row = tid;
        unsigned int m = 0xFFFFFFFFu;
        #pragma unroll
        for (int ww = 0; ww < 2; ++ww)
            for (int t = 0; t < 16; ++t) m = min(m, P1[ww][row][t]);
        float lim = unpackscore(m) + MARG;
        int cand[NCAND]; int nc = 0;
        for (int ww = 0; ww < 2; ++ww)
            for (int t = 0; t < 16; ++t) {
                unsigned int a1 = P1[ww][row][t], a2 = P2[ww][row][t];
                if (unpackscore(a1) <= lim && nc < NCAND) cand[nc++] = (int)(a1 & 0xFFFu);
                if (unpackscore(a2) <= lim && nc < NCAND) cand[nc++] = (int)(a2 & 0xFFFu);
            }
        // numpy-fp32 emulated rescore (verbatim from R5/R6 — validated exact)
        const float* xr = X + (size_t)(row0 + row) * DD;
        float xs = xsqw[row0 + row];
        float bd = 3.0e38f; int bk = 0x7fffffff;
        for (int cidx = 0; cidx < nc; ++cidx) {
            int k = cand[cidx] & (KK - 1);
            const float* er = E + (size_t)k * DD;
            float q1 = 0.f, q2 = 0.f;
            for (int d = 0; d < 384; ++d)   q1 = fmaf(xr[d], er[d], q1);
            for (int d = 384; d < 512; ++d) q2 = fmaf(xr[d], er[d], q2);
            float dot = __fadd_rn(q1, q2);
            float t1  = __fadd_rn(xs, esqw[k]);
            float dnp = __fsub_rn(t1, __fmul_rn(2.0f, dot));
            if (dnp < bd || (dnp == bd && k < bk)) { bd = dnp; bk = k; }
        }
        const float* er = E + (size_t)bk * DD;
        double ls = 0.0;
        for (int d = 0; d < DD; ++d) {
            double df = (double)xr[d] - (double)er[d];
            ls = fma(df, df, ls);
        }
        lsr[row] = ls;
        sidx[row] = bk;
        idxbuf[row0 + row] = bk;
        out[IDX_OFF + row0 + row] = (float)bk;
        atomicAdd(&hist[bk], 1);
    }
    __syncthreads();
    // quantized_st = codebook gather, fp32
    for (int e = tid; e < 32 * DD / 4; e += 128) {
        int r = e >> 7, d = (e & 127) * 4;
        int ci = sidx[r];
        float4 q4 = *(const float4*)&E[(size_t)ci * DD + d];
        *(float4*)&out[(size_t)(row0 + r) * DD + d] = q4;
    }
    if (tid == 0) {
        double s = 0.0;
        #pragma unroll 8
        for (int i = 0; i < 32; ++i) s += lsr[i];
        atomicAdd(loss_acc, s);
    }
}

__global__ __launch_bounds__(256) void enc_kernel(const int* __restrict__ idxbuf,
                                                  float* __restrict__ out) {
    int row = blockIdx.x;
    int idx = idxbuf[row];
    float2* erow = (float2*)(out + ENC_OFF) + (size_t)row * (KK / 2);
    int half = idx >> 1;
    float2 one;
    if (idx & 1) { one.x = 0.f; one.y = 1.f; } else { one.x = 1.f; one.y = 0.f; }
    float2 z; z.x = 0.f; z.y = 0.f;
    for (int c = threadIdx.x; c < KK / 2; c += 256)
        erow[c] = (c == half) ? one : z;
}

__global__ __launch_bounds__(256) void fin_kernel(const int* __restrict__ hist,
                                                  const double* __restrict__ loss_acc,
                                                  float* __restrict__ out) {
    __shared__ double red[256];
    int tid = threadIdx.x;
    double s = 0.0;
    for (int k = tid; k < KK; k += 256) {
        double p = (double)hist[k] * (1.0 / 32768.0);
        s += p * log(p + 1e-10);
    }
    red[tid] = s;
    __syncthreads();
    for (int t = 128; t > 0; t >>= 1) {
        if (tid < t) red[tid] += red[tid + t];
        __syncthreads();
    }
    if (tid == 0) {
        double perp = exp(-red[0]);
        double L = loss_acc[0] * (1.0 / ((double)BB * (double)DD));
        out[LOSS_OFF] = (float)(1.25 * L);
        out[PERP_OFF] = (float)perp;
    }
}

extern "C" void kernel_launch(void* const* d_in, const int* in_sizes, int n_in,
                              void* d_out, int out_size, void* d_ws, size_t ws_size,
                              hipStream_t stream) {
    const float* X; const float* E;
    if (in_sizes[0] == BB * DD) { X = (const float*)d_in[0]; E = (const float*)d_in[1]; }
    else                        { X = (const float*)d_in[1]; E = (const float*)d_in[0]; }
    float* out = (float*)d_out;

    float* xsq = (float*)((char*)d_ws + WSB_XSQ);
    float* esq = (float*)((char*)d_ws + WSB_ESQ);
    int* idxbuf = (int*)((char*)d_ws + WSB_IDX);
    int* hist   = (int*)((char*)d_ws + WSB_HIST);
    double* loss_acc = (double*)((char*)d_ws + WSB_LOSS);
    unsigned short* Ebf = (unsigned short*)((char*)d_ws + WSB_EBF);

    hipLaunchKernelGGL(init_kernel, dim3(16), dim3(256), 0, stream, hist, loss_acc);
    hipLaunchKernelGGL(npsum_kernel, dim3((BB + KK) / 4), dim3(256), 0, stream,
                       X, E, xsq, esq);
    hipLaunchKernelGGL(ecvt_kernel, dim3(1024), dim3(256), 0, stream, E, Ebf);
    hipLaunchKernelGGL(vq_mfma, dim3(BB / 32), dim3(128), 0, stream,
                       X, E, Ebf, xsq, esq, idxbuf, hist, loss_acc, out);
    hipLaunchKernelGGL(enc_kernel, dim3(BB), dim3(256), 0, stream, idxbuf, out);
    hipLaunchKernelGGL(fin_kernel, dim3(1), dim3(256), 0, stream, hist, loss_acc, out);
}

// Round 8
// 463.006 us; speedup vs baseline: 5.2330x; 1.2507x over previous
//
#include <hip/hip_runtime.h>
#include <hip/hip_bf16.h>

// VectorQuantizer B=32768, K=4096, D=512, fp32 in/out.
// Out concat (f32): quantized_st[B*512] | indices[B] | loss | perplexity | encodings[B*4096].
// R8: K-split MFMA screen. 4 waves/block = (kw,cw): col-half x K-half. afrag 64 VGPR
// -> fits 128-VGPR budget -> 4 waves/SIMD; per-cf partial-acc exchange via 2-slot
// LDS (one barrier/cf). Packed top-2 screen + numpy-fp32 rescore (validated R5-R7).

typedef __attribute__((ext_vector_type(8))) short bf16x8;
typedef __attribute__((ext_vector_type(4))) float f32x4;

#define BB 32768
#define KK 4096
#define DD 512

#define IDX_OFF  (BB*DD)
#define LOSS_OFF (IDX_OFF + BB)
#define PERP_OFF (LOSS_OFF + 1)
#define ENC_OFF  (PERP_OFF + 1)

// ws byte offsets
#define WSB_XSQ  0
#define WSB_ESQ  131072
#define WSB_IDX  147456
#define WSB_HIST 278528
#define WSB_LOSS 294912
#define WSB_EBF  294928        // 4 MB bf16 codebook, fragment-packed

#define MARG 2.5e-4f
#define NCAND 24

static __device__ __forceinline__ unsigned short f2bf(float f) {
    __hip_bfloat16 h = __float2bfloat16(f);
    return *reinterpret_cast<unsigned short*>(&h);
}

// monotone-packed score: high 20 bits order-preserving float, low 12 col
static __device__ __forceinline__ unsigned int packscore(float s, int col) {
    unsigned int u = __float_as_uint(s);
    u ^= (u & 0x80000000u) ? 0xFFFFFFFFu : 0x80000000u;
    return (u & 0xFFFFF000u) | (unsigned int)col;
}
static __device__ __forceinline__ float unpackscore(unsigned int p) {
    unsigned int u = p & 0xFFFFF000u;
    u = (u & 0x80000000u) ? (u ^ 0x80000000u) : ~u;
    return __uint_as_float(u);
}

__global__ __launch_bounds__(256) void init_kernel(int* __restrict__ hist,
                                                   double* __restrict__ loss_acc) {
    int i = blockIdx.x * 256 + threadIdx.x;
    if (i < KK) hist[i] = 0;
    if (i == 0) *loss_acc = 0.0;
}

// numpy-emulated row sum-of-squares (pairwise-128 + AVX512 lane fold) — validated R5-R7
__global__ __launch_bounds__(256) void npsum_kernel(const float* __restrict__ X,
                                                    const float* __restrict__ E,
                                                    float* __restrict__ xsq,
                                                    float* __restrict__ esq) {
    __shared__ float sq[4][512];
    __shared__ float ub[4][64];
    __shared__ float bb[4][4];
    int w = threadIdx.x >> 6, lane = threadIdx.x & 63;
    int row = blockIdx.x * 4 + w;
    const float* src; float* dst;
    if (row < BB) { src = X + (size_t)row * DD;        dst = xsq + row; }
    else          { src = E + (size_t)(row - BB) * DD; dst = esq + (row - BB); }
    #pragma unroll
    for (int m = 0; m < 8; ++m) {
        float v = src[m * 64 + lane];
        sq[w][m * 64 + lane] = __fmul_rn(v, v);
    }
    __syncthreads();
    {
        int b = lane >> 4, l = lane & 15;
        const float* s = &sq[w][b * 128];
        float t = __fadd_rn(
            __fadd_rn(__fadd_rn(s[l], s[16 + l]), __fadd_rn(s[32 + l], s[48 + l])),
            __fadd_rn(__fadd_rn(s[64 + l], s[80 + l]), __fadd_rn(s[96 + l], s[112 + l])));
        ub[w][lane] = t;
    }
    __syncthreads();
    if (lane < 4) {
        const float* u = &ub[w][lane * 16];
        float T3[8], T6[4];
        #pragma unroll
        for (int i = 0; i < 8; ++i) T3[i] = __fadd_rn(u[i], u[i + 8]);
        #pragma unroll
        for (int i = 0; i < 4; ++i) T6[i] = __fadd_rn(T3[i], T3[i + 4]);
        bb[w][lane] = __fadd_rn(__fadd_rn(T6[0], T6[2]), __fadd_rn(T6[1], T6[3]));
    }
    __syncthreads();
    if (lane == 0)
        *dst = __fadd_rn(__fadd_rn(bb[w][0], bb[w][1]), __fadd_rn(bb[w][2], bb[w][3]));
}

// codebook fp32 -> bf16, FRAGMENT-PACKED: bf16x8 index ((cf*16+ks)*64 + lane)
// holds E[cf*16 + (lane&15)][ks*32 + (lane>>4)*8 + 0..7].
__global__ __launch_bounds__(256) void ecvt_kernel(const float* __restrict__ E,
                                                   unsigned short* __restrict__ Ebf) {
    int t = blockIdx.x * 256 + threadIdx.x;     // 262144 threads
    int lane = t & 63, rest = t >> 6;
    int ks = rest & 15, cf = rest >> 4;
    int c = lane & 15, g = lane >> 4;
    const float* src = E + (size_t)(cf * 16 + c) * DD + ks * 32 + g * 8;
    float4 a = ((const float4*)src)[0], b = ((const float4*)src)[1];
    union { bf16x8 v; unsigned short u[8]; } pk;
    pk.u[0] = f2bf(a.x); pk.u[1] = f2bf(a.y); pk.u[2] = f2bf(a.z); pk.u[3] = f2bf(a.w);
    pk.u[4] = f2bf(b.x); pk.u[5] = f2bf(b.y); pk.u[6] = f2bf(b.z); pk.u[7] = f2bf(b.w);
    *(bf16x8*)(Ebf + (size_t)t * 8) = pk.v;
}

// main: K-split bf16 MFMA screen -> numpy-fp32 rescore -> epilogues.
// 256 thr = 4 waves; wave w: kw=w>>1 (K-half), cw=w&1 (col-half). Rows/block 32.
__global__ __launch_bounds__(256, 4) void vq_mfma(
    const float* __restrict__ X, const float* __restrict__ E,
    const unsigned short* __restrict__ Ebf,
    const float* __restrict__ xsqw, const float* __restrict__ esqw,
    int* __restrict__ idxbuf, int* __restrict__ hist,
    double* __restrict__ loss_acc, float* __restrict__ out)
{
    __shared__ f32x4 xch[2][4][64];             // 8 KB acc-exchange, 2 slots
    __shared__ unsigned int P1[2][32][16];      // 4 KB
    __shared__ unsigned int P2[2][32][16];      // 4 KB
    __shared__ int    sidx[32];
    __shared__ double lsr[32];

    const int tid  = threadIdx.x;
    const int w    = tid >> 6;
    const int kw   = w >> 1;        // K-half: k in [kw*256, kw*256+256)
    const int cw   = w & 1;         // col-half: cf in [cw*128, cw*128+128)
    const int lane = tid & 63;
    const int c    = lane & 15;
    const int g    = lane >> 4;
    const int row0 = blockIdx.x * 32;

    // A fragments for this wave's K-half: rows rf*16+c
    bf16x8 afrag[2][8];
    #pragma unroll
    for (int rf = 0; rf < 2; ++rf) {
        const float* xrow = X + (size_t)(row0 + rf * 16 + c) * DD + kw * 256;
        #pragma unroll
        for (int ks = 0; ks < 8; ++ks) {
            const float4* s = (const float4*)(xrow + ks * 32 + g * 8);
            float4 a = s[0], b = s[1];
            union { bf16x8 v; unsigned short u[8]; } pk;
            pk.u[0] = f2bf(a.x); pk.u[1] = f2bf(a.y);
            pk.u[2] = f2bf(a.z); pk.u[3] = f2bf(a.w);
            pk.u[4] = f2bf(b.x); pk.u[5] = f2bf(b.y);
            pk.u[6] = f2bf(b.z); pk.u[7] = f2bf(b.w);
            afrag[rf][ks] = pk.v;
        }
    }

    unsigned int p1[4], p2[4];
    #pragma unroll
    for (int r = 0; r < 4; ++r) { p1[r] = 0xFFFFFFFFu; p2[r] = 0xFFFFFFFFu; }

    for (int cfl = 0; cfl < 128; ++cfl) {
        const int cf = cw * 128 + cfl;
        const bf16x8* bsrc = (const bf16x8*)Ebf + ((size_t)(cf * 16 + kw * 8)) * 64 + lane;
        f32x4 acc0 = (f32x4){0.f, 0.f, 0.f, 0.f};
        f32x4 acc1 = (f32x4){0.f, 0.f, 0.f, 0.f};
        #pragma unroll
        for (int ks = 0; ks < 8; ++ks) {
            bf16x8 b = bsrc[ks * 64];
            acc0 = __builtin_amdgcn_mfma_f32_16x16x32_bf16(afrag[0][ks], b, acc0, 0, 0, 0);
            acc1 = __builtin_amdgcn_mfma_f32_16x16x32_bf16(afrag[1][ks], b, acc1, 0, 0, 0);
        }
        const int slot = cfl & 1;
        xch[slot][w][lane] = kw ? acc0 : acc1;   // ship the rf we don't own
        __syncthreads();
        f32x4 oth  = xch[slot][w ^ 2][lane];
        f32x4 mine = kw ? acc1 : acc0;           // rf == kw
        const int col = cf * 16 + c;
        const float esqc = esqw[col];
        #pragma unroll
        for (int r = 0; r < 4; ++r) {
            float s = fmaf(-2.0f, __fadd_rn(mine[r], oth[r]), esqc);
            unsigned int q = packscore(s, col);
            if (q < p1[r]) { p2[r] = p1[r]; p1[r] = q; }
            else if (q < p2[r]) p2[r] = q;
        }
    }

    // merge: wave (kw,cw) owns rows kw*16 + g*4 + r, col-slot c
    __syncthreads();
    #pragma unroll
    for (int r = 0; r < 4; ++r) {
        int row = kw * 16 + g * 4 + r;
        P1[cw][row][c] = p1[r];
        P2[cw][row][c] = p2[r];
    }
    __syncthreads();

    if (tid < 32) {
        const int row = tid;
        unsigned int m = 0xFFFFFFFFu;
        #pragma unroll
        for (int ww = 0; ww < 2; ++ww)
            for (int t = 0; t < 16; ++t) m = min(m, P1[ww][row][t]);
        float lim = unpackscore(m) + MARG;
        int cand[NCAND]; int nc = 0;
        for (int ww = 0; ww < 2; ++ww)
            for (int t = 0; t < 16; ++t) {
                unsigned int a1 = P1[ww][row][t], a2 = P2[ww][row][t];
                if (unpackscore(a1) <= lim && nc < NCAND) cand[nc++] = (int)(a1 & 0xFFFu);
                if (unpackscore(a2) <= lim && nc < NCAND) cand[nc++] = (int)(a2 & 0xFFFu);
            }
        // numpy-fp32 emulated rescore (verbatim, validated R5-R7)
        const float* xr = X + (size_t)(row0 + row) * DD;
        float xs = xsqw[row0 + row];
        float bd = 3.0e38f; int bk = 0x7fffffff;
        for (int cidx = 0; cidx < nc; ++cidx) {
            int k = cand[cidx] & (KK - 1);
            const float* er = E + (size_t)k * DD;
            float q1 = 0.f, q2 = 0.f;
            for (int d = 0; d < 384; ++d)   q1 = fmaf(xr[d], er[d], q1);
            for (int d = 384; d < 512; ++d) q2 = fmaf(xr[d], er[d], q2);
            float dot = __fadd_rn(q1, q2);
            float t1  = __fadd_rn(xs, esqw[k]);
            float dnp = __fsub_rn(t1, __fmul_rn(2.0f, dot));
            if (dnp < bd || (dnp == bd && k < bk)) { bd = dnp; bk = k; }
        }
        const float* er = E + (size_t)bk * DD;
        double ls = 0.0;
        for (int d = 0; d < DD; ++d) {
            double df = (double)xr[d] - (double)er[d];
            ls = fma(df, df, ls);
        }
        lsr[row] = ls;
        sidx[row] = bk;
        idxbuf[row0 + row] = bk;
        out[IDX_OFF + row0 + row] = (float)bk;
        atomicAdd(&hist[bk], 1);
    }
    __syncthreads();
    // quantized_st = codebook gather, fp32
    for (int e = tid; e < 32 * DD / 4; e += 256) {
        int r = e >> 7, d = (e & 127) * 4;
        int ci = sidx[r];
        float4 q4 = *(const float4*)&E[(size_t)ci * DD + d];
        *(float4*)&out[(size_t)(row0 + r) * DD + d] = q4;
    }
    if (tid == 0) {
        double s = 0.0;
        #pragma unroll 8
        for (int i = 0; i < 32; ++i) s += lsr[i];
        atomicAdd(loss_acc, s);
    }
}

__global__ __launch_bounds__(256) void enc_kernel(const int* __restrict__ idxbuf,
                                                  float* __restrict__ out) {
    int row = blockIdx.x;
    int idx = idxbuf[row];
    float2* erow = (float2*)(out + ENC_OFF) + (size_t)row * (KK / 2);
    int half = idx >> 1;
    float2 one;
    if (idx & 1) { one.x = 0.f; one.y = 1.f; } else { one.x = 1.f; one.y = 0.f; }
    float2 z; z.x = 0.f; z.y = 0.f;
    for (int c = threadIdx.x; c < KK / 2; c += 256)
        erow[c] = (c == half) ? one : z;
}

__global__ __launch_bounds__(256) void fin_kernel(const int* __restrict__ hist,
                                                  const double* __restrict__ loss_acc,
                                                  float* __restrict__ out) {
    __shared__ double red[256];
    int tid = threadIdx.x;
    double s = 0.0;
    for (int k = tid; k < KK; k += 256) {
        double p = (double)hist[k] * (1.0 / 32768.0);
        s += p * log(p + 1e-10);
    }
    red[tid] = s;
    __syncthreads();
    for (int t = 128; t > 0; t >>= 1) {
        if (tid < t) red[tid] += red[tid + t];
        __syncthreads();
    }
    if (tid == 0) {
        double perp = exp(-red[0]);
        double L = loss_acc[0] * (1.0 / ((double)BB * (double)DD));
        out[LOSS_OFF] = (float)(1.25 * L);
        out[PERP_OFF] = (float)perp;
    }
}

extern "C" void kernel_launch(void* const* d_in, const int* in_sizes, int n_in,
                              void* d_out, int out_size, void* d_ws, size_t ws_size,
                              hipStream_t stream) {
    const float* X; const float* E;
    if (in_sizes[0] == BB * DD) { X = (const float*)d_in[0]; E = (const float*)d_in[1]; }
    else                        { X = (const float*)d_in[1]; E = (const float*)d_in[0]; }
    float* out = (float*)d_out;

    float* xsq = (float*)((char*)d_ws + WSB_XSQ);
    float* esq = (float*)((char*)d_ws + WSB_ESQ);
    int* idxbuf = (int*)((char*)d_ws + WSB_IDX);
    int* hist   = (int*)((char*)d_ws + WSB_HIST);
    double* loss_acc = (double*)((char*)d_ws + WSB_LOSS);
    unsigned short* Ebf = (unsigned short*)((char*)d_ws + WSB_EBF);

    hipLaunchKernelGGL(init_kernel, dim3(16), dim3(256), 0, stream, hist, loss_acc);
    hipLaunchKernelGGL(npsum_kernel, dim3((BB + KK) / 4), dim3(256), 0, stream,
                       X, E, xsq, esq);
    hipLaunchKernelGGL(ecvt_kernel, dim3(1024), dim3(256), 0, stream, E, Ebf);
    hipLaunchKernelGGL(vq_mfma, dim3(BB / 32), dim3(256), 0, stream,
                       X, E, Ebf, xsq, esq, idxbuf, hist, loss_acc, out);
    hipLaunchKernelGGL(enc_kernel, dim3(BB), dim3(256), 0, stream, idxbuf, out);
    hipLaunchKernelGGL(fin_kernel, dim3(1), dim3(256), 0, stream, hist, loss_acc, out);
}